// Round 2
// baseline (169.670 us; speedup 1.0000x reference)
//
#include <hip/hip_runtime.h>
#include <hip/hip_bf16.h>

#define VOCAB 100000
#define EMBED 64
#define SENT  20
#define MEM   50
#define BATCH 32
#define HOPS  3

// 4 gather sets per batch: t=0 -> A (m for hop0); t=1..3 -> C[t-1]
// (c for hop t-1, m for hop t). Exploits m_h == c_{h-1}.
#define NSET   4
#define NSLOTB (NSET * MEM)      // 200 sentence slots per batch
#define LDSP   65                // stride-65: both row & col LDS views conflict-free

__device__ __forceinline__ float bfr(unsigned short x) {
    union { unsigned int u; float f; } cv;
    cv.u = ((unsigned int)x) << 16;
    return cv.f;
}

// Runtime dtype probe: enc row 19 (last) is exactly 1.0 everywhere.
// bf16 storage: dword 639 packs elements 1278,1279 = (1.0bf,1.0bf) = 0x3F803F80.
__device__ __forceinline__ bool is_bf16(const void* enc) {
    return ((const unsigned int*)enc)[639] == 0x3F803F80u;
}

template<bool BF>
__device__ __forceinline__ float ldT(const void* p, size_t idx) {
    if constexpr (BF) return bfr(((const unsigned short*)p)[idx]);
    else              return ((const float*)p)[idx];
}

__device__ __forceinline__ float wave_sum(float d) {
#pragma unroll
    for (int off = 32; off > 0; off >>= 1) d += __shfl_xor(d, off, 64);
    return d;
}

// ---- all 201 gathers for batch b, results into LDS (dtype branch hoisted) ----
// mc[(t*MEM+mm)*65 + e] = sum_s T_t[w_s][e] * enc[s][e];  uls[e] = u0[b][e]
template<bool BF>
__device__ __forceinline__ void gather_all(const int* __restrict__ stories,
                                           const int* __restrict__ queries,
                                           const void* __restrict__ A,
                                           const void* __restrict__ C,
                                           const void* __restrict__ enc,
                                           float* __restrict__ mc,
                                           float* __restrict__ uls,
                                           int b)
{
    const int tid = threadIdx.x;
    const int e   = tid & 63;
    const int w   = tid >> 6;              // wave 0..15
    const size_t VE = (size_t)VOCAB * EMBED;

    float encr[SENT];
#pragma unroll
    for (int s = 0; s < SENT; ++s) encr[s] = ldT<BF>(enc, s * EMBED + e);

    // 201 slots round-robin over 16 waves; slot 200 (= 8 + 16*12) is the query.
    for (int slot = w; slot < NSLOTB + 1; slot += 16) {
        if (slot < NSLOTB) {
            const int t  = slot / MEM;
            const int mm = slot % MEM;
            const void* T   = (t == 0) ? A : C;
            const size_t to = (t == 0) ? 0 : (size_t)(t - 1) * VE;

            int wst = (e < SENT) ? stories[(b * MEM + mm) * SENT + e] : 0;
            float acc = 0.f;
#pragma unroll
            for (int s = 0; s < SENT; ++s) {
                int wd = __shfl(wst, s, 64);
                acc += ldT<BF>(T, to + (size_t)wd * EMBED + e) * encr[s];
            }
            mc[(t * MEM + mm) * LDSP + e] = acc;
        } else {
            int wq = (e < SENT) ? queries[b * SENT + e] : 0;
            float u = 0.f;
#pragma unroll
            for (int s = 0; s < SENT; ++s) {
                int wd = __shfl(wq, s, 64);
                u += ldT<BF>(A, (size_t)wd * EMBED + e) * encr[s];
            }
            uls[e] = u;
        }
    }
}

// ---- Kernel 1: one block per batch (1024 thr = 16 waves).
// Gathers -> LDS, then 3-hop recurrence from LDS, write u3[b] (64 floats).
// No grid sync, no atomics, no global mc round-trip.
__global__ __launch_bounds__(1024) void k_front(
    const int* __restrict__ stories,   // [32,50,20]
    const int* __restrict__ queries,   // [32,20]
    const void* __restrict__ A,        // [V,64]
    const void* __restrict__ C,        // [3,V,64]
    const void* __restrict__ enc,      // [20,64]
    float* __restrict__ u3g)           // [32,64]
{
    __shared__ float mc[NSET * MEM * LDSP];   // 52 KB
    __shared__ float uls[EMBED];
    __shared__ float ols[4][EMBED];

    const bool bf = is_bf16(enc);
    const int b   = blockIdx.x;
    const int tid = threadIdx.x;

    if (bf) gather_all<true >(stories, queries, A, C, enc, mc, uls, b);
    else    gather_all<false>(stories, queries, A, C, enc, mc, uls, b);
    __syncthreads();

    const int lane = tid & 63;
    const int widx = tid >> 6;     // 0..15; only waves 0..3 compute

    for (int hop = 0; hop < HOPS; ++hop) {
        if (tid < 256) {
            // dot: lane mm computes <m[mm], u> (waves 0..3 redundantly)
            float d = 0.f;
            if (lane < MEM) {
                const float* row = mc + (hop * MEM + lane) * LDSP;
#pragma unroll
                for (int e2 = 0; e2 < EMBED; ++e2) d += row[e2] * uls[e2];
            }
            // softmax over lanes 0..49 (in-lane, per wave)
            float x  = (lane < MEM) ? d : -3.4e38f;
            float mx = x;
#pragma unroll
            for (int off = 32; off > 0; off >>= 1) mx = fmaxf(mx, __shfl_xor(mx, off, 64));
            float ex = (lane < MEM) ? __expf(x - mx) : 0.f;
            float sm = wave_sum(ex);
            float p  = ex / sm;

            // weighted sum: wave w covers mm = 13w .. 13w+12 (w3: 39..49)
            float o = 0.f;
            const float* crow = mc + ((hop + 1) * MEM) * LDSP;
#pragma unroll
            for (int k = 0; k < 13; ++k) {
                int mm = widx * 13 + k;
                if (mm < MEM)
                    o += __shfl(p, mm, 64) * crow[mm * LDSP + lane];
            }
            ols[widx][lane] = o;
        }
        __syncthreads();
        if (tid < EMBED)
            uls[tid] += ols[0][tid] + ols[1][tid] + ols[2][tid] + ols[3][tid];
        __syncthreads();
    }

    if (tid < EMBED) u3g[b * EMBED + tid] = uls[tid];
}

// ---- Kernel 2: out[b*V+v] = sum_e u3[b][e] * C[2][v][e]  (proven R2 version) ----
template<bool BF>
__device__ __forceinline__ void out_one(const float* __restrict__ su,
                                        const void* __restrict__ Cbase,
                                        void* __restrict__ out, int v)
{
    const size_t c2_off = (size_t)2 * VOCAB * EMBED;
    float row[EMBED];
    if constexpr (BF) {
        const uint4* rp = (const uint4*)((const unsigned short*)Cbase + c2_off + (size_t)v * EMBED);
#pragma unroll
        for (int i = 0; i < 8; ++i) {
            uint4 r = rp[i];
            row[i*8 + 0] = bfr((unsigned short)(r.x & 0xffff));
            row[i*8 + 1] = bfr((unsigned short)(r.x >> 16));
            row[i*8 + 2] = bfr((unsigned short)(r.y & 0xffff));
            row[i*8 + 3] = bfr((unsigned short)(r.y >> 16));
            row[i*8 + 4] = bfr((unsigned short)(r.z & 0xffff));
            row[i*8 + 5] = bfr((unsigned short)(r.z >> 16));
            row[i*8 + 6] = bfr((unsigned short)(r.w & 0xffff));
            row[i*8 + 7] = bfr((unsigned short)(r.w >> 16));
        }
    } else {
        const float4* rp = (const float4*)((const float*)Cbase + c2_off + (size_t)v * EMBED);
#pragma unroll
        for (int i = 0; i < 16; ++i) {
            float4 r = rp[i];
            row[i*4 + 0] = r.x; row[i*4 + 1] = r.y;
            row[i*4 + 2] = r.z; row[i*4 + 3] = r.w;
        }
    }

    float res[BATCH];
#pragma unroll
    for (int bb = 0; bb < BATCH; ++bb) {
        const float4* sp = (const float4*)(su + bb * EMBED);
        float acc = 0.f;
#pragma unroll
        for (int e4 = 0; e4 < 16; ++e4) {
            float4 us = sp[e4];
            acc += row[e4*4+0]*us.x + row[e4*4+1]*us.y
                 + row[e4*4+2]*us.z + row[e4*4+3]*us.w;
        }
        res[bb] = acc;
    }

    if constexpr (BF) {
        unsigned short* ob = (unsigned short*)out;
#pragma unroll
        for (int bb = 0; bb < BATCH; ++bb) {
            __hip_bfloat16 h = __float2bfloat16(res[bb]);
            ob[(size_t)bb * VOCAB + v] = *(unsigned short*)&h;
        }
    } else {
        float* of = (float*)out;
#pragma unroll
        for (int bb = 0; bb < BATCH; ++bb)
            of[(size_t)bb * VOCAB + v] = res[bb];
    }
}

__global__ __launch_bounds__(256) void k_out(const float* __restrict__ u,
                                             const void* __restrict__ Cbase,
                                             const void* __restrict__ enc,
                                             void* __restrict__ out)
{
    const bool bf = is_bf16(enc);
    __shared__ __align__(16) float su[BATCH * EMBED];
    for (int i = threadIdx.x; i < BATCH * EMBED; i += 256) su[i] = u[i];
    __syncthreads();
    const int v = blockIdx.x * 256 + threadIdx.x;
    if (v >= VOCAB) return;
    if (bf) out_one<true >(su, Cbase, enc ? out : out, v);
    else    out_one<false>(su, Cbase, out, v);
}

extern "C" void kernel_launch(void* const* d_in, const int* in_sizes, int n_in,
                              void* d_out, int out_size, void* d_ws, size_t ws_size,
                              hipStream_t stream)
{
    const int*  stories = (const int*)d_in[0];
    const int*  queries = (const int*)d_in[1];
    const void* A       = d_in[2];
    const void* C       = d_in[3];
    const void* enc     = d_in[4];

    float* u3g = (float*)d_ws;   // [32,64]

    k_front<<<BATCH, 1024, 0, stream>>>(stories, queries, A, C, enc, u3g);
    k_out<<<(VOCAB + 255) / 256, 256, 0, stream>>>(u3g, C, enc, d_out);
}